// Round 11
// baseline (272.049 us; speedup 1.0000x reference)
//
#include <hip/hip_runtime.h>

// ROUND 10 = DIAGNOSTIC ROUND (round-9 resubmit, compile fix: nontemporal
// builtin needs a clang ext-vector type, not HIP's float4 struct).
// Two dispatches:
//  1) copy_probe: pure grid-stride float4 copy d_in -> d_out (the m13
//     6.3 TB/s microbench pattern, 262 MB of traffic). rocprof reports its
//     dispatch duration separately.
//     -> ~42us (~6 TB/s): rounds 1-8's 2.4 TB/s plateau is kernel-structural.
//     -> ~100us (~2.4 TB/s): rounds 1-8 were at the true roofline.
//  2) sinkhorn16_kernel: round-8 LDS-staged kernel (overwrites d_out with
//     correct values -> validation preserved). Single change vs R8:
//     NONTEMPORAL stage-out stores (bypass cache allocation) to test whether
//     L3 write-allocate pollution (input 128MB + output 128MB ~ 256MB L3)
//     throttles the write stream.

#define NITER 10
typedef float v2f __attribute__((ext_vector_type(2)));
typedef float v4f __attribute__((ext_vector_type(4)));

template <int CTRL>
__device__ __forceinline__ float dpp_add(float x) {
    int xi = __builtin_bit_cast(int, x);
    int yi = __builtin_amdgcn_update_dpp(xi, xi, CTRL, 0xF, 0xF, false);
    return x + __builtin_bit_cast(float, yi);
}

__global__ __launch_bounds__(256) void copy_probe(
        const v4f* __restrict__ src, v4f* __restrict__ dst, int n4) {
    int idx = blockIdx.x * 256 + threadIdx.x;
    const int stride = gridDim.x * 256;
    for (; idx < n4; idx += stride) dst[idx] = src[idx];
}

__global__ __launch_bounds__(256) void sinkhorn16_kernel(
        const float* __restrict__ v, float* __restrict__ out, int nmat) {
    __shared__ float lds[4096];                       // 16 matrices = 16 KB
    v4f* lds4 = (v4f*)lds;

    const int t       = threadIdx.x;
    const int blk_mat = blockIdx.x * 16;
    const v4f* g4     = (const v4f*)(v + (size_t)blk_mat * 256);
    v4f* o4           = (v4f*)(out + (size_t)blk_mat * 256);

    // ---- stage in: contiguous 1KB per wave-instruction ----
#pragma unroll
    for (int k = 0; k < 4; ++k) {
        const int i4 = k * 256 + t;
        lds4[i4] = g4[i4];
    }
    __syncthreads();

    // ---- gather strided fragments from LDS ----
    const int m_blk = t >> 4;          // matrix 0..15 within block
    const int idx   = t & 15;
    const int r     = idx & 3;
    const int c     = idx >> 2;

    v4f fj[4];                         // fj[j] = v[m][4c+j][4r..4r+3]
#pragma unroll
    for (int j = 0; j < 4; ++j)
        fj[j] = lds4[m_blk * 64 + (4 * c + j) * 4 + r];

    // bp[i][j2] = (blk[i][2*j2], blk[i][2*j2+1]) + 1e-6
    v2f bp[4][2];
#pragma unroll
    for (int j2 = 0; j2 < 2; ++j2) {
        const v4f fa = fj[2 * j2], fb = fj[2 * j2 + 1];
        bp[0][j2] = (v2f){fa.x + 1e-6f, fb.x + 1e-6f};
        bp[1][j2] = (v2f){fa.y + 1e-6f, fb.y + 1e-6f};
        bp[2][j2] = (v2f){fa.z + 1e-6f, fb.z + 1e-6f};
        bp[3][j2] = (v2f){fa.w + 1e-6f, fb.w + 1e-6f};
    }

    float rv[4] = {1.0f, 1.0f, 1.0f, 1.0f};
    v2f cjp[2];

#pragma unroll
    for (int it = 0; it < NITER; ++it) {
        // ---- column phase: c_j = 1/sum_i S0[i][j]*r_i ----
#pragma unroll
        for (int j2 = 0; j2 < 2; ++j2) {
            v2f acc = bp[0][j2] * (v2f){rv[0], rv[0]};
            acc += bp[1][j2] * (v2f){rv[1], rv[1]};
            acc += bp[2][j2] * (v2f){rv[2], rv[2]};
            acc += bp[3][j2] * (v2f){rv[3], rv[3]};
            float s0 = dpp_add<0x4E>(dpp_add<0xB1>(acc.x));   // xor 1, xor 2
            float s1 = dpp_add<0x4E>(dpp_add<0xB1>(acc.y));
            cjp[j2] = (v2f){__builtin_amdgcn_rcpf(s0), __builtin_amdgcn_rcpf(s1)};
        }
        // ---- row phase: r_i = 1/sum_j S0[i][j]*c_j ----
#pragma unroll
        for (int i = 0; i < 4; ++i) {
            v2f tacc = bp[i][0] * cjp[0] + bp[i][1] * cjp[1];
            float s = dpp_add<0x128>(dpp_add<0x124>(tacc.x + tacc.y)); // ror 4,8
            rv[i] = __builtin_amdgcn_rcpf(s);
        }
    }

    // ---- results back to LDS ----
#pragma unroll
    for (int i = 0; i < 4; ++i) {
        const v2f rvp = (v2f){rv[i], rv[i]};
        const v2f s0 = bp[i][0] * cjp[0] * rvp;
        const v2f s1 = bp[i][1] * cjp[1] * rvp;
        lds4[m_blk * 64 + (4 * r + i) * 4 + c] = (v4f){s0.x, s0.y, s1.x, s1.y};
    }
    __syncthreads();

    // ---- stage out: contiguous, NONTEMPORAL (bypass cache allocation) ----
#pragma unroll
    for (int k = 0; k < 4; ++k) {
        const int i4 = k * 256 + t;
        __builtin_nontemporal_store(lds4[i4], &o4[i4]);
    }
}

extern "C" void kernel_launch(void* const* d_in, const int* in_sizes, int n_in,
                              void* d_out, int out_size, void* d_ws, size_t ws_size,
                              hipStream_t stream) {
    const float* v = (const float*)d_in[0];
    float* out = (float*)d_out;
    const int nmat = in_sizes[0] >> 8;            // 131072
    const int n4   = in_sizes[0] >> 2;            // 8,388,608 float4s

    // Dispatch 1: roofline reference probe (d_out fully overwritten after).
    copy_probe<<<2048, 256, 0, stream>>>((const v4f*)v, (v4f*)out, n4);

    // Dispatch 2: the real computation.
    const int grid = nmat / 16;                   // 8192
    sinkhorn16_kernel<<<grid, 256, 0, stream>>>(v, out, nmat);
}

// Round 12
// 228.313 us; speedup vs baseline: 1.1916x; 1.1916x over previous
//
#include <hip/hip_runtime.h>

// Batched 16x16 Sinkhorn (VotingLayer), scaling-vector algorithm, LDS-staged
// coalesced I/O (round-8 structure) + NONTEMPORAL loads AND stores.
//
// Round-11 diagnostic: a pure float4 copy probe pins at the same ~2.5 TB/s
// as every kernel variant (R8 sinkhorn = copy + 4-8%), while the harness's
// own 537MB poison-fill runs at 6.8 TB/s (write-only). Theory: the pre-replay
// poison leaves L3 100% dirty; every read miss / write-allocate must evict a
// dirty victim (fetch serialized behind writeback) -> read path caps ~2.5.
// This round: `nt` on both streams to bypass L3 allocation entirely
// (streaming read + streaming write, no victim churn). If neutral, we are at
// the environmental roofline (kernel ~= memcpy) and the session is done.

#define NITER 10
typedef float v2f __attribute__((ext_vector_type(2)));
typedef float v4f __attribute__((ext_vector_type(4)));

template <int CTRL>
__device__ __forceinline__ float dpp_add(float x) {
    int xi = __builtin_bit_cast(int, x);
    int yi = __builtin_amdgcn_update_dpp(xi, xi, CTRL, 0xF, 0xF, false);
    return x + __builtin_bit_cast(float, yi);
}

__global__ __launch_bounds__(256) void sinkhorn16_kernel(
        const float* __restrict__ v, float* __restrict__ out, int nmat) {
    __shared__ float lds[4096];                       // 16 matrices = 16 KB
    v4f* lds4 = (v4f*)lds;

    const int t       = threadIdx.x;
    const int blk_mat = blockIdx.x * 16;
    const v4f* g4     = (const v4f*)(v + (size_t)blk_mat * 256);
    v4f* o4           = (v4f*)(out + (size_t)blk_mat * 256);

    // ---- stage in: contiguous 1KB per wave-instruction, NONTEMPORAL ----
#pragma unroll
    for (int k = 0; k < 4; ++k) {
        const int i4 = k * 256 + t;
        lds4[i4] = __builtin_nontemporal_load(&g4[i4]);
    }
    __syncthreads();

    // ---- gather strided fragments from LDS ----
    const int m_blk = t >> 4;          // matrix 0..15 within block
    const int idx   = t & 15;
    const int r     = idx & 3;
    const int c     = idx >> 2;

    v4f fj[4];                         // fj[j] = v[m][4c+j][4r..4r+3]
#pragma unroll
    for (int j = 0; j < 4; ++j)
        fj[j] = lds4[m_blk * 64 + (4 * c + j) * 4 + r];

    // bp[i][j2] = (blk[i][2*j2], blk[i][2*j2+1]) + 1e-6
    v2f bp[4][2];
#pragma unroll
    for (int j2 = 0; j2 < 2; ++j2) {
        const v4f fa = fj[2 * j2], fb = fj[2 * j2 + 1];
        bp[0][j2] = (v2f){fa.x + 1e-6f, fb.x + 1e-6f};
        bp[1][j2] = (v2f){fa.y + 1e-6f, fb.y + 1e-6f};
        bp[2][j2] = (v2f){fa.z + 1e-6f, fb.z + 1e-6f};
        bp[3][j2] = (v2f){fa.w + 1e-6f, fb.w + 1e-6f};
    }

    float rv[4] = {1.0f, 1.0f, 1.0f, 1.0f};
    v2f cjp[2];

#pragma unroll
    for (int it = 0; it < NITER; ++it) {
        // ---- column phase: c_j = 1/sum_i S0[i][j]*r_i ----
#pragma unroll
        for (int j2 = 0; j2 < 2; ++j2) {
            v2f acc = bp[0][j2] * (v2f){rv[0], rv[0]};
            acc += bp[1][j2] * (v2f){rv[1], rv[1]};
            acc += bp[2][j2] * (v2f){rv[2], rv[2]};
            acc += bp[3][j2] * (v2f){rv[3], rv[3]};
            float s0 = dpp_add<0x4E>(dpp_add<0xB1>(acc.x));   // xor 1, xor 2
            float s1 = dpp_add<0x4E>(dpp_add<0xB1>(acc.y));
            cjp[j2] = (v2f){__builtin_amdgcn_rcpf(s0), __builtin_amdgcn_rcpf(s1)};
        }
        // ---- row phase: r_i = 1/sum_j S0[i][j]*c_j ----
#pragma unroll
        for (int i = 0; i < 4; ++i) {
            v2f tacc = bp[i][0] * cjp[0] + bp[i][1] * cjp[1];
            float s = dpp_add<0x128>(dpp_add<0x124>(tacc.x + tacc.y)); // ror 4,8
            rv[i] = __builtin_amdgcn_rcpf(s);
        }
    }

    // ---- results back to LDS ----
#pragma unroll
    for (int i = 0; i < 4; ++i) {
        const v2f rvp = (v2f){rv[i], rv[i]};
        const v2f s0 = bp[i][0] * cjp[0] * rvp;
        const v2f s1 = bp[i][1] * cjp[1] * rvp;
        lds4[m_blk * 64 + (4 * r + i) * 4 + c] = (v4f){s0.x, s0.y, s1.x, s1.y};
    }
    __syncthreads();

    // ---- stage out: contiguous 1KB per wave-instruction, NONTEMPORAL ----
#pragma unroll
    for (int k = 0; k < 4; ++k) {
        const int i4 = k * 256 + t;
        __builtin_nontemporal_store(lds4[i4], &o4[i4]);
    }
}

extern "C" void kernel_launch(void* const* d_in, const int* in_sizes, int n_in,
                              void* d_out, int out_size, void* d_ws, size_t ws_size,
                              hipStream_t stream) {
    const float* v = (const float*)d_in[0];
    float* out = (float*)d_out;
    const int nmat = in_sizes[0] >> 8;            // 131072
    const int grid = nmat / 16;                   // 16 matrices per block -> 8192
    sinkhorn16_kernel<<<grid, 256, 0, stream>>>(v, out, nmat);
}